// Round 4
// baseline (293.797 us; speedup 1.0000x reference)
//
#include <hip/hip_runtime.h>

// Problem constants
#define MROWS 512            // B*S
#define VDIM  50257          // vocab
#define KP    50304          // VDIM padded to multiple of 64 (= 64*786)
#define NDIM  1024           // D
#define NST64 786            // KP/64 K-steps of 64
#define KSPLIT 32
#define SC     25            // ceil(786/32)
#define PRED_OFF 524288      // 512*1024
#define PP_OFF   524800      // + 512
#define NPREP  4096          // 512 rows x 8 chunks
#define CHUNK  6284          // multiple of 4; 8*6284 >= VDIM
#define NCONVW 12576         // 786*16 transpose tiles

typedef unsigned short u16;
typedef unsigned int   u32;
typedef unsigned long long u64;
typedef __bf16 bf16x8 __attribute__((ext_vector_type(8)));
typedef float  f32x4  __attribute__((ext_vector_type(4)));
typedef float  f32x4u __attribute__((ext_vector_type(4), aligned(4)));

__device__ __forceinline__ u16 f2bf(float f) {
  u32 u = __float_as_uint(f);
  u32 r = (u + 0x7fffu + ((u >> 16) & 1u)) >> 16;  // RNE
  return (u16)r;
}

__device__ __forceinline__ void gl_lds16(const u16* g, u16* l) {
  __builtin_amdgcn_global_load_lds(
      (const __attribute__((address_space(1))) u32*)(g),
      (__attribute__((address_space(3))) u32*)(l), 16, 0, 0);
}

// ---------------------------------------------------------------------------
// Fused prep, interleaved 1 prep-chunk : 3 convw blocks so the P-stream and
// W-stream mix across the whole dispatch (no low-BW tail).
// prep chunk: aligned copy+argmax pass, then cache-hot bf16-convert pass.
// ---------------------------------------------------------------------------
__global__ __launch_bounds__(256) void prep_fused(const float* __restrict__ P,
                                                  const float* __restrict__ W,
                                                  float* __restrict__ out,
                                                  u16* __restrict__ A,
                                                  u16* __restrict__ BT,
                                                  u64* __restrict__ amax)
{
  const int tid = threadIdx.x;
  const int bx  = blockIdx.x;
  const bool is_prep = ((bx & 3) == 0) && (bx < 16384);

  if (is_prep) {
    const int pidx = bx >> 2;           // 0..4095
    const int m  = pidx >> 3;
    const int c  = pidx & 7;
    const int s0 = c * CHUNK;
    const int len = min(VDIM - s0, CHUNK);
    const float* row = P + (size_t)m * VDIM;      // row base
    float*       crw = out + PP_OFF + (size_t)m * VDIM;
    u16*        arow = A + (size_t)m * KP;

    // zero this block's slice of pred_emb row m (128 floats)
    if (tid < 32) { f32x4 z = {}; *(f32x4*)(out + (size_t)m * NDIM + c * 128 + tid * 4) = z; }

    u64 best = 0;  // packed (f32 bits << 32) | (0xFFFF - idx); p>0 so bits>0
#define TRK(val, idx) do { \
      u64 pk = ((u64)__float_as_uint(val) << 32) | (u64)(0xFFFFu - (u32)(idx)); \
      best = best > pk ? best : pk; } while (0)

    // ---- pass 1: 16B-aligned copy + argmax ----
    // flat addr phase: (m*VDIM + col) % 4 == 0 when col ≡ (-m) mod 4
    const int h0 = (-m) & 3;            // head elems (s0 % 4 == 0)
    if (tid < h0) {
      const int col = s0 + tid;
      float v = row[col]; crw[col] = v; TRK(v, col);
    }
    const int ca = s0 + h0;
    const int nv = (len - h0) >> 2;
    for (int i = tid; i < nv; i += 256) {
      const int col = ca + (i << 2);
      f32x4 v = *(const f32x4*)(row + col);       // fully aligned both sides
      *(f32x4*)(crw + col) = v;
      TRK(v[0], col); TRK(v[1], col + 1); TRK(v[2], col + 2); TRK(v[3], col + 3);
    }
    const int tc = (len - h0) & 3;
    if (tid < tc) {
      const int col = ca + (nv << 2) + tid;
      float v = row[col]; crw[col] = v; TRK(v, col);
    }
#undef TRK

    // ---- pass 2: bf16 convert (reads are L1/L2-hot), aligned ushort4 store ----
    const int nv2 = len >> 2;
    for (int i = tid; i < nv2; i += 256) {
      const int col = s0 + (i << 2);
      f32x4u v = *(const f32x4u*)(row + col);
      ushort4 o;
      o.x = f2bf(v[0]); o.y = f2bf(v[1]); o.z = f2bf(v[2]); o.w = f2bf(v[3]);
      *(ushort4*)(arow + col) = o;                // col%4==0, KP even -> 8B aligned
    }
    if ((len & 3) && tid == 0) {
      const int col = s0 + (len & ~3);
      arow[col] = f2bf(row[col]);
    }
    if (c == 7 && tid < KP - VDIM) arow[VDIM + tid] = 0;  // K-pad (47 elems)

    // block argmax reduction -> one atomic
    __shared__ u64 sb[256];
    sb[tid] = best;
    __syncthreads();
    for (int s = 128; s > 0; s >>= 1) {
      if (tid < s) { u64 o = sb[tid + s]; if (o > sb[tid]) sb[tid] = o; }
      __syncthreads();
    }
    if (tid == 0) atomicMax(&amax[m], sb[0]);
  } else {
    // ---- convw: 64x64 tile transpose via LDS ----
    const int cidx = (bx < 16384) ? (bx - 1 - (bx >> 2)) : (bx - NPREP);
    __shared__ u16 t[64][65];
    const int dt  = cidx & 15;
    const int vt  = cidx >> 4;          // 0..785, 786*64 == KP exactly
    const int v0  = vt << 6;
    const int d0  = dt << 6;
    const int c16 = tid & 15;
    const int r16 = tid >> 4;
#pragma unroll
    for (int p = 0; p < 4; ++p) {
      const int v  = v0 + p * 16 + r16;
      const int vl = p * 16 + r16;
      float4 w = make_float4(0.f, 0.f, 0.f, 0.f);
      if (v < VDIM) w = *(const float4*)(W + (size_t)v * NDIM + d0 + c16 * 4);
      t[c16 * 4 + 0][vl] = f2bf(w.x);
      t[c16 * 4 + 1][vl] = f2bf(w.y);
      t[c16 * 4 + 2][vl] = f2bf(w.z);
      t[c16 * 4 + 3][vl] = f2bf(w.w);
    }
    __syncthreads();
#pragma unroll
    for (int p = 0; p < 4; ++p) {
      const int dl = p * 16 + r16;
      const int vl = c16 * 4;
      ushort4 o;
      o.x = t[dl][vl]; o.y = t[dl][vl + 1]; o.z = t[dl][vl + 2]; o.w = t[dl][vl + 3];
      *(ushort4*)(BT + (size_t)(d0 + dl) * KP + v0 + vl) = o;
    }
  }
}

// ---------------------------------------------------------------------------
// GEMM: 256x256 tile, BK=64, 8 waves (2m x 4n), dbuf LDS 128KB, counted-vmcnt
// pipeline (stage 2 steps ahead, vmcnt(8) mid-loop, never 0), 8-slot XOR
// swizzle (pre-swizzled global source + swizzled ds_read), split-K=32,
// XCD-grouped decode, atomicAdd f32 epilogue.
// ---------------------------------------------------------------------------
__global__ __launch_bounds__(512, 2) void gemm_kernel(const u16* __restrict__ A,
                                                      const u16* __restrict__ BT,
                                                      const u64* __restrict__ amax,
                                                      float* __restrict__ out)
{
  __shared__ u16 ldsA[2][256 * 64];   // 32KB per buf
  __shared__ u16 ldsB[2][256 * 64];

  const int bx  = blockIdx.x;
  // bits[2:0]=x, [5:3]=mn, [7:6]=z; kc = x | z<<3 -> the 8 mn-blocks of one kc
  // all have bx%8==x -> same XCD (shared A/B k-panels stay in one L2)
  const int kc  = (bx & 7) | ((bx >> 6) << 3);
  const int mn  = (bx >> 3) & 7;
  const int m0  = (mn & 1) << 8;
  const int n0  = (mn >> 1) << 8;
  const int ks0 = kc * SC;
  const int ks1 = min(NST64, ks0 + SC);
  const int tid  = threadIdx.x;
  const int wid  = tid >> 6;
  const int lane = tid & 63;
  const int wr   = wid >> 2;   // 0..1
  const int wc   = wid & 3;    // 0..3

  if (bx == 0) {  // finalize predictions (512 threads, one per row)
    u64 p = amax[tid];
    out[PRED_OFF + tid] = (float)(0xFFFF - (int)(p & 0xFFFFu));
  }

  // staging: per gl_lds16, lane l covers row_local=l>>3, slot=l&7 (16B slots).
  // LDS is written linearly (base + lane*16B); swizzle realized by fetching
  // global k-block (slot ^ row&7) so LDS slot s of row r holds block s^(r&7).
  const int srow8 = lane >> 3;                 // 0..7
  const int gk    = ((lane & 7) ^ srow8) << 3; // swizzled k-offset (elems)
  const u16* gA = A  + (size_t)(m0 + wid * 32 + srow8) * KP + gk;
  const u16* gB = BT + (size_t)(n0 + wid * 32 + srow8) * KP + gk;

  f32x4 acc[8][4] = {};

  // fragment read indices
  const int r   = lane & 15;
  const int q4  = lane >> 4;                   // 0..3 k-quarter
  const int sw  = r & 7;
  const int s0r = (q4 ^ sw) << 3;              // k-half 0 slot (elems)
  const int s1r = ((4 + q4) ^ sw) << 3;        // k-half 1 slot
  const int rbA = (wr * 128 + r) * 64;
  const int rbB = (wc * 64 + r) * 64;

#define STAGE(buf, ks) do {                                              \
    const size_t k_ = (size_t)(ks) << 6;                                 \
    _Pragma("unroll")                                                    \
    for (int q = 0; q < 4; ++q) {                                        \
      gl_lds16(gA + k_ + (size_t)(q * 8) * KP,                           \
               &ldsA[buf][(wid * 32 + q * 8) * 64]);                     \
      gl_lds16(gB + k_ + (size_t)(q * 8) * KP,                           \
               &ldsB[buf][(wid * 32 + q * 8) * 64]);                     \
    }                                                                    \
  } while (0)

  STAGE(0, ks0);
  if (ks0 + 1 < ks1) STAGE(1, ks0 + 1);

  int cur = 0;
  for (int ks = ks0; ks < ks1; ++ks) {
    if (ks + 1 < ks1) asm volatile("s_waitcnt vmcnt(8)" ::: "memory");
    else              asm volatile("s_waitcnt vmcnt(0)" ::: "memory");
    __builtin_amdgcn_s_barrier();    // buf[cur] landed for ALL waves

    const u16* lA = ldsA[cur];
    const u16* lB = ldsB[cur];

    bf16x8 a0[8], b0[4];
#pragma unroll
    for (int i = 0; i < 8; ++i) a0[i] = *(const bf16x8*)(lA + rbA + i * 1024 + s0r);
#pragma unroll
    for (int j = 0; j < 4; ++j) b0[j] = *(const bf16x8*)(lB + rbB + j * 1024 + s0r);
    __builtin_amdgcn_s_setprio(1);
#pragma unroll
    for (int i = 0; i < 8; ++i)
#pragma unroll
      for (int j = 0; j < 4; ++j)
        acc[i][j] = __builtin_amdgcn_mfma_f32_16x16x32_bf16(a0[i], b0[j], acc[i][j], 0, 0, 0);
    __builtin_amdgcn_s_setprio(0);

    bf16x8 a1[8], b1[4];
#pragma unroll
    for (int i = 0; i < 8; ++i) a1[i] = *(const bf16x8*)(lA + rbA + i * 1024 + s1r);
#pragma unroll
    for (int j = 0; j < 4; ++j) b1[j] = *(const bf16x8*)(lB + rbB + j * 1024 + s1r);
    __builtin_amdgcn_s_setprio(1);
#pragma unroll
    for (int i = 0; i < 8; ++i)
#pragma unroll
      for (int j = 0; j < 4; ++j)
        acc[i][j] = __builtin_amdgcn_mfma_f32_16x16x32_bf16(a1[i], b1[j], acc[i][j], 0, 0, 0);
    __builtin_amdgcn_s_setprio(0);

    __builtin_amdgcn_s_barrier();    // all waves done reading buf[cur]
    if (ks + 2 < ks1) STAGE(cur, ks + 2);   // overwrite just-freed buffer
    cur ^= 1;
  }
#undef STAGE

  // epilogue: split-K accumulate (pred_emb zeroed by prep)
  const int col = lane & 15;
  const int r4  = q4 << 2;
#pragma unroll
  for (int i = 0; i < 8; ++i)
#pragma unroll
    for (int j = 0; j < 4; ++j)
#pragma unroll
      for (int rr = 0; rr < 4; ++rr) {
        const int mm = m0 + wr * 128 + i * 16 + r4 + rr;
        const int nn = n0 + wc * 64 + j * 16 + col;
        atomicAdd(out + (size_t)mm * NDIM + nn, acc[i][j][rr]);
      }
}

// ---------------------------------------------------------------------------
extern "C" void kernel_launch(void* const* d_in, const int* in_sizes, int n_in,
                              void* d_out, int out_size, void* d_ws, size_t ws_size,
                              hipStream_t stream) {
  const float* P = (const float*)d_in[0];   // [512][50257]
  const float* W = (const float*)d_in[1];   // [50257][1024]
  float* out = (float*)d_out;
  u64* amax = (u64*)d_ws;                               // 512 x u64
  u16* A  = (u16*)((char*)d_ws + 4096);                 // [512][KP] bf16
  u16* BT = A + (size_t)MROWS * KP;                     // [1024][KP] bf16

  hipMemsetAsync(amax, 0, MROWS * sizeof(u64), stream);
  prep_fused<<<NPREP + NCONVW, 256, 0, stream>>>(P, W, out, A, BT, amax);
  gemm_kernel<<<256, 512, 0, stream>>>(A, BT, amax, out);
}

// Round 5
// 236.973 us; speedup vs baseline: 1.2398x; 1.2398x over previous
//
#include <hip/hip_runtime.h>

// Problem constants
#define MROWS 512            // B*S
#define VDIM  50257          // vocab
#define KP    50304          // VDIM padded to multiple of 64 (= 64*786)
#define NDIM  1024           // D
#define NST32 1572           // KP/32 K-steps of 32
#define KSPLIT 32
#define SC     50            // ceil(1572/32)=50; 32*50=1600>=1572, all chunks nonempty
#define PRED_OFF 524288      // 512*1024
#define PP_OFF   524800      // + 512
#define NPREP  4096          // 512 rows x 8 chunks
#define CHUNK  6284          // multiple of 4; 8*6284 >= VDIM
#define NCONVW 12576         // 786*16 transpose tiles

typedef unsigned short u16;
typedef unsigned int   u32;
typedef unsigned long long u64;
typedef __bf16 bf16x8 __attribute__((ext_vector_type(8)));
typedef float  f32x4  __attribute__((ext_vector_type(4)));
typedef float  f32x4u __attribute__((ext_vector_type(4), aligned(4)));

__device__ __forceinline__ u16 f2bf(float f) {
  u32 u = __float_as_uint(f);
  u32 r = (u + 0x7fffu + ((u >> 16) & 1u)) >> 16;  // RNE
  return (u16)r;
}

__device__ __forceinline__ void gl_lds16(const u16* g, u16* l) {
  __builtin_amdgcn_global_load_lds(
      (const __attribute__((address_space(1))) u32*)(g),
      (__attribute__((address_space(3))) u32*)(l), 16, 0, 0);
}

// ---------------------------------------------------------------------------
// Fused prep (R3 ordering: prep chunks first, convw after).
// prep chunk: SINGLE pass — load P quad once, copy + bf16-cvt + argmax;
// unroll-2 so two independent 16B loads are in flight per lane (MLP).
// ---------------------------------------------------------------------------
__global__ __launch_bounds__(256) void prep_fused(const float* __restrict__ P,
                                                  const float* __restrict__ W,
                                                  float* __restrict__ out,
                                                  u16* __restrict__ A,
                                                  u16* __restrict__ BT,
                                                  u64* __restrict__ amax)
{
  const int tid = threadIdx.x;
  const int bx  = blockIdx.x;
  if (bx < NPREP) {
    const int m  = bx >> 3;
    const int c  = bx & 7;
    const int s0 = c * CHUNK;
    const int len = min(VDIM - s0, CHUNK);
    const float* row = P + (size_t)m * VDIM;
    float*       crw = out + PP_OFF + (size_t)m * VDIM;
    u16*        arow = A + (size_t)m * KP;

    // zero this block's slice of pred_emb row m (128 floats)
    if (tid < 32) { f32x4 z = {}; *(f32x4*)(out + (size_t)m * NDIM + c * 128 + tid * 4) = z; }

    u64 best = 0;  // packed (f32 bits << 32) | (0xFFFF - idx); p>0 so bits>0
#define TRK(val, idx) do { \
      u64 pk = ((u64)__float_as_uint(val) << 32) | (u64)(0xFFFFu - (u32)(idx)); \
      best = best > pk ? best : pk; } while (0)

    const int nvec = len >> 2;           // quads; col = s0+4i -> arow 8B-aligned
    int i = tid;
    for (; i + 256 < nvec; i += 512) {   // two independent loads per iter
      const int c0 = s0 + (i << 2);
      const int c1 = c0 + 1024;
      f32x4u v0 = *(const f32x4u*)(row + c0);
      f32x4u v1 = *(const f32x4u*)(row + c1);
      *(f32x4u*)(crw + c0) = v0;
      *(f32x4u*)(crw + c1) = v1;
      ushort4 o0, o1;
      o0.x = f2bf(v0[0]); o0.y = f2bf(v0[1]); o0.z = f2bf(v0[2]); o0.w = f2bf(v0[3]);
      o1.x = f2bf(v1[0]); o1.y = f2bf(v1[1]); o1.z = f2bf(v1[2]); o1.w = f2bf(v1[3]);
      *(ushort4*)(arow + c0) = o0;
      *(ushort4*)(arow + c1) = o1;
      TRK(v0[0], c0); TRK(v0[1], c0 + 1); TRK(v0[2], c0 + 2); TRK(v0[3], c0 + 3);
      TRK(v1[0], c1); TRK(v1[1], c1 + 1); TRK(v1[2], c1 + 2); TRK(v1[3], c1 + 3);
    }
    if (i < nvec) {                      // remainder quad
      const int c0 = s0 + (i << 2);
      f32x4u v = *(const f32x4u*)(row + c0);
      *(f32x4u*)(crw + c0) = v;
      ushort4 o;
      o.x = f2bf(v[0]); o.y = f2bf(v[1]); o.z = f2bf(v[2]); o.w = f2bf(v[3]);
      *(ushort4*)(arow + c0) = o;
      TRK(v[0], c0); TRK(v[1], c0 + 1); TRK(v[2], c0 + 2); TRK(v[3], c0 + 3);
    }
    if ((len & 3) && tid == 0) {         // last chunk straggler (1 elem)
      const int col = s0 + (len & ~3);
      float v = row[col];
      crw[col] = v;
      arow[col] = f2bf(v);
      TRK(v, col);
    }
#undef TRK
    if (c == 7 && tid < KP - VDIM) arow[VDIM + tid] = 0;  // K-pad (47 elems)

    __shared__ u64 sb[256];
    sb[tid] = best;
    __syncthreads();
    for (int s = 128; s > 0; s >>= 1) {
      if (tid < s) { u64 o = sb[tid + s]; if (o > sb[tid]) sb[tid] = o; }
      __syncthreads();
    }
    if (tid == 0) atomicMax(&amax[m], sb[0]);
  } else {
    // ---- convw: 64x64 tile transpose via LDS ----
    const int cidx = bx - NPREP;
    __shared__ u16 t[64][65];
    const int dt  = cidx & 15;
    const int vt  = cidx >> 4;          // 0..785; 786*64 == KP exactly
    const int v0  = vt << 6;
    const int d0  = dt << 6;
    const int c16 = tid & 15;
    const int r16 = tid >> 4;
#pragma unroll
    for (int p = 0; p < 4; ++p) {
      const int v  = v0 + p * 16 + r16;
      const int vl = p * 16 + r16;
      float4 w = make_float4(0.f, 0.f, 0.f, 0.f);
      if (v < VDIM) w = *(const float4*)(W + (size_t)v * NDIM + d0 + c16 * 4);
      t[c16 * 4 + 0][vl] = f2bf(w.x);
      t[c16 * 4 + 1][vl] = f2bf(w.y);
      t[c16 * 4 + 2][vl] = f2bf(w.z);
      t[c16 * 4 + 3][vl] = f2bf(w.w);
    }
    __syncthreads();
#pragma unroll
    for (int p = 0; p < 4; ++p) {
      const int dl = p * 16 + r16;
      const int vl = c16 * 4;
      ushort4 o;
      o.x = t[dl][vl]; o.y = t[dl][vl + 1]; o.z = t[dl][vl + 2]; o.w = t[dl][vl + 3];
      *(ushort4*)(BT + (size_t)(d0 + dl) * KP + v0 + vl) = o;
    }
  }
}

// ---------------------------------------------------------------------------
// GEMM: 256x256 tile, BK=32, 8 waves (2m x 4n), 4-buffer LDS ring (128KB),
// depth-3 prefetch with counted vmcnt (8/4/0), ONE barrier per K-step,
// 4-slot XOR swizzle (pre-swizzled global source + swizzled ds_read),
// split-K=32, XCD-grouped decode, atomicAdd f32 epilogue.
// ---------------------------------------------------------------------------
__global__ __launch_bounds__(512, 1) void gemm_kernel(const u16* __restrict__ A,
                                                      const u16* __restrict__ BT,
                                                      const u64* __restrict__ amax,
                                                      float* __restrict__ out)
{
  __shared__ u16 ldsA[4][256 * 32];   // 16KB per buf
  __shared__ u16 ldsB[4][256 * 32];

  const int bx  = blockIdx.x;
  // bits[2:0]=x, [5:3]=mn, [7:6]=z; kc = x | z<<3 -> the 8 mn-blocks of one kc
  // all have bx%8==x -> same XCD (shared A/B k-panels stay in one L2)
  const int kc  = (bx & 7) | ((bx >> 6) << 3);     // 0..31
  const int mn  = (bx >> 3) & 7;
  const int m0  = (mn & 1) << 8;
  const int n0  = (mn >> 1) << 8;
  const int ks0 = kc * SC;
  const int ks1 = min(NST32, ks0 + SC);
  const int tid  = threadIdx.x;
  const int wid  = tid >> 6;
  const int lane = tid & 63;
  const int wr   = wid >> 2;   // 0..1
  const int wc   = wid & 3;    // 0..3

  if (bx == 0) {  // finalize predictions (512 threads, one per row)
    u64 p = amax[tid];
    out[PRED_OFF + tid] = (float)(0xFFFF - (int)(p & 0xFFFFu));
  }

  // staging: lane l covers row_local=l>>2, slot=l&3 (16B slots of 64B rows).
  // LDS written linearly (base + lane*16B); swizzle realized by fetching
  // global k-block (slot ^ (row&3)) so LDS slot s of row r holds block s^(r&3).
  const int srow4 = lane >> 2;                   // 0..15
  const int gk    = ((lane & 3) ^ (srow4 & 3)) << 3;  // swizzled k-off (elems)
  const u16* gA = A  + (size_t)(m0 + wid * 32 + srow4) * KP + gk;
  const u16* gB = BT + (size_t)(n0 + wid * 32 + srow4) * KP + gk;

  f32x4 acc[8][4] = {};

  // fragment read indices: row r, k-quarter q4, swizzled slot
  const int r   = lane & 15;
  const int q4  = lane >> 4;                     // 0..3
  const int s0r = ((q4 ^ (r & 3)) << 3);         // elems
  const int rbA = (wr * 128 + r) * 32;
  const int rbB = (wc * 64 + r) * 32;

#define STAGE(buf, ks) do {                                           \
    const size_t k_ = (size_t)(ks) << 5;                              \
    gl_lds16(gA + k_,                 &ldsA[buf][(wid * 32) * 32]);   \
    gl_lds16(gA + k_ + (size_t)16*KP, &ldsA[buf][(wid * 32 + 16) * 32]); \
    gl_lds16(gB + k_,                 &ldsB[buf][(wid * 32) * 32]);   \
    gl_lds16(gB + k_ + (size_t)16*KP, &ldsB[buf][(wid * 32 + 16) * 32]); \
  } while (0)

  STAGE(0, ks0);
  if (ks0 + 1 < ks1) STAGE(1, ks0 + 1);
  if (ks0 + 2 < ks1) STAGE(2, ks0 + 2);

  int b = 0;
  for (int ks = ks0; ks < ks1; ++ks) {
    // wait for stage ks (counted: stages ks+1, ks+2 may stay in flight)
    if (ks + 2 < ks1)      asm volatile("s_waitcnt vmcnt(8) lgkmcnt(0)" ::: "memory");
    else if (ks + 1 < ks1) asm volatile("s_waitcnt vmcnt(4) lgkmcnt(0)" ::: "memory");
    else                   asm volatile("s_waitcnt vmcnt(0) lgkmcnt(0)" ::: "memory");
    __builtin_amdgcn_s_barrier();
    // barrier also proves step ks-1 reads done -> safe to overwrite buf (b+3)&3
    if (ks + 3 < ks1) STAGE((b + 3) & 3, ks + 3);

    const u16* lA = ldsA[b];
    const u16* lB = ldsB[b];
    bf16x8 av[8], bv[4];
#pragma unroll
    for (int i = 0; i < 8; ++i) av[i] = *(const bf16x8*)(lA + rbA + i * 16 * 32 + s0r);
#pragma unroll
    for (int j = 0; j < 4; ++j) bv[j] = *(const bf16x8*)(lB + rbB + j * 16 * 32 + s0r);

    __builtin_amdgcn_s_setprio(1);
#pragma unroll
    for (int i = 0; i < 8; ++i)
#pragma unroll
      for (int j = 0; j < 4; ++j)
        acc[i][j] = __builtin_amdgcn_mfma_f32_16x16x32_bf16(av[i], bv[j], acc[i][j], 0, 0, 0);
    __builtin_amdgcn_s_setprio(0);
    __builtin_amdgcn_sched_barrier(0);  // pin MFMAs (and their lgkm waits) here
    b = (b + 1) & 3;
  }
#undef STAGE

  // epilogue: split-K accumulate (pred_emb zeroed by prep)
  const int col = lane & 15;
  const int r4  = q4 << 2;
#pragma unroll
  for (int i = 0; i < 8; ++i)
#pragma unroll
    for (int j = 0; j < 4; ++j)
#pragma unroll
      for (int rr = 0; rr < 4; ++rr) {
        const int mm = m0 + wr * 128 + i * 16 + r4 + rr;
        const int nn = n0 + wc * 64 + j * 16 + col;
        atomicAdd(out + (size_t)mm * NDIM + nn, acc[i][j][rr]);
      }
}

// ---------------------------------------------------------------------------
extern "C" void kernel_launch(void* const* d_in, const int* in_sizes, int n_in,
                              void* d_out, int out_size, void* d_ws, size_t ws_size,
                              hipStream_t stream) {
  const float* P = (const float*)d_in[0];   // [512][50257]
  const float* W = (const float*)d_in[1];   // [50257][1024]
  float* out = (float*)d_out;
  u64* amax = (u64*)d_ws;                               // 512 x u64
  u16* A  = (u16*)((char*)d_ws + 4096);                 // [512][KP] bf16
  u16* BT = A + (size_t)MROWS * KP;                     // [1024][KP] bf16

  hipMemsetAsync(amax, 0, MROWS * sizeof(u64), stream);
  prep_fused<<<NPREP + NCONVW, 256, 0, stream>>>(P, W, out, A, BT, amax);
  gemm_kernel<<<256, 512, 0, stream>>>(A, BT, amax, out);
}

// Round 6
// 223.589 us; speedup vs baseline: 1.3140x; 1.0599x over previous
//
#include <hip/hip_runtime.h>

// Problem constants
#define MROWS 512            // B*S
#define VDIM  50257          // vocab
#define KP    50304          // VDIM padded to multiple of 64 (= 64*786)
#define NDIM  1024           // D
#define NST32 1572           // KP/32 K-steps of 32
#define KSPLIT 32
#define SC     25            // ceil(786*2/32/2)=25 steps of 32 per kc (last=11)
#define PRED_OFF 524288      // 512*1024
#define PP_OFF   524800      // + 512
#define NPREP  4096          // 512 rows x 8 chunks
#define CHUNK  6288          // multiple of 8; 8*6288 >= VDIM
#define NCONVW 12576         // 786*16 transpose tiles

typedef unsigned short u16;
typedef unsigned int   u32;
typedef unsigned long long u64;
typedef __bf16 bf16x8 __attribute__((ext_vector_type(8)));
typedef u16    u16x8  __attribute__((ext_vector_type(8)));
typedef float  f32x4  __attribute__((ext_vector_type(4)));
typedef float  f32x4u __attribute__((ext_vector_type(4), aligned(4)));

__device__ __forceinline__ u16 f2bf(float f) {
  u32 u = __float_as_uint(f);
  u32 r = (u + 0x7fffu + ((u >> 16) & 1u)) >> 16;  // RNE
  return (u16)r;
}

__device__ __forceinline__ void gl_lds16(const u16* g, u16* l) {
  __builtin_amdgcn_global_load_lds(
      (const __attribute__((address_space(1))) u32*)(g),
      (__attribute__((address_space(3))) u32*)(l), 16, 0, 0);
}

// ---------------------------------------------------------------------------
// Fused prep: blocks [0,NPREP) = P row-chunks (copy + argmax + bf16, single
// pass, 8-elem groups -> 16B A-stores, 4 loads in flight); then convw.
// ---------------------------------------------------------------------------
__global__ __launch_bounds__(256) void prep_fused(const float* __restrict__ P,
                                                  const float* __restrict__ W,
                                                  float* __restrict__ out,
                                                  u16* __restrict__ A,
                                                  u16* __restrict__ BT,
                                                  u64* __restrict__ amax)
{
  const int tid = threadIdx.x;
  const int bx  = blockIdx.x;
  if (bx < NPREP) {
    const int m  = bx >> 3;
    const int c  = bx & 7;
    const int s0 = c * CHUNK;
    const int len = min(VDIM - s0, CHUNK);       // 6288, last chunk 6241
    const float* row = P + (size_t)m * VDIM;
    float*       crw = out + PP_OFF + (size_t)m * VDIM;
    u16*        arow = A + (size_t)m * KP;

    if (tid < 32) { f32x4 z = {}; *(f32x4*)(out + (size_t)m * NDIM + c * 128 + tid * 4) = z; }

    u64 best = 0;  // packed (f32 bits << 32) | (0xFFFF - idx); p>0 so bits>0
#define TRK(val, idx) do { \
      u64 pk = ((u64)__float_as_uint(val) << 32) | (u64)(0xFFFFu - (u32)(idx)); \
      best = best > pk ? best : pk; } while (0)
#define GRP(cc) do {                                                     \
      f32x4u va = *(const f32x4u*)(row + (cc));                          \
      f32x4u vb = *(const f32x4u*)(row + (cc) + 4);                      \
      *(f32x4u*)(crw + (cc))     = va;                                   \
      *(f32x4u*)(crw + (cc) + 4) = vb;                                   \
      u16x8 o;                                                           \
      o[0]=f2bf(va[0]); o[1]=f2bf(va[1]); o[2]=f2bf(va[2]); o[3]=f2bf(va[3]); \
      o[4]=f2bf(vb[0]); o[5]=f2bf(vb[1]); o[6]=f2bf(vb[2]); o[7]=f2bf(vb[3]); \
      *(u16x8*)(arow + (cc)) = o;                                        \
      TRK(va[0],(cc)); TRK(va[1],(cc)+1); TRK(va[2],(cc)+2); TRK(va[3],(cc)+3); \
      TRK(vb[0],(cc)+4); TRK(vb[1],(cc)+5); TRK(vb[2],(cc)+6); TRK(vb[3],(cc)+7); \
    } while (0)

    const int ng = len >> 3;                     // 8-elem groups
    int i = tid;
    for (; i + 256 < ng; i += 512) {             // 4 loads in flight
      const int c0 = s0 + (i << 3);
      const int c1 = c0 + 2048;
      GRP(c0);
      GRP(c1);
    }
    if (i < ng) GRP(s0 + (i << 3));
    if (tid < (len & 7)) {                       // straggler elems (last chunk)
      const int col = s0 + (ng << 3) + tid;
      float v = row[col];
      crw[col] = v;
      arow[col] = f2bf(v);
      TRK(v, col);
    }
#undef GRP
#undef TRK
    if (c == 7 && tid < KP - VDIM) arow[VDIM + tid] = 0;  // K-pad (47 elems)

    __shared__ u64 sb[256];
    sb[tid] = best;
    __syncthreads();
    for (int s = 128; s > 0; s >>= 1) {
      if (tid < s) { u64 o = sb[tid + s]; if (o > sb[tid]) sb[tid] = o; }
      __syncthreads();
    }
    if (tid == 0) atomicMax(&amax[m], sb[0]);
  } else {
    // ---- convw: 64x64 tile transpose via LDS ----
    const int cidx = bx - NPREP;
    __shared__ u16 t[64][65];
    const int dt  = cidx & 15;
    const int vt  = cidx >> 4;          // 0..785; 786*64 == KP exactly
    const int v0  = vt << 6;
    const int d0  = dt << 6;
    const int c16 = tid & 15;
    const int r16 = tid >> 4;
#pragma unroll
    for (int p = 0; p < 4; ++p) {
      const int v  = v0 + p * 16 + r16;
      const int vl = p * 16 + r16;
      float4 w = make_float4(0.f, 0.f, 0.f, 0.f);
      if (v < VDIM) w = *(const float4*)(W + (size_t)v * NDIM + d0 + c16 * 4);
      t[c16 * 4 + 0][vl] = f2bf(w.x);
      t[c16 * 4 + 1][vl] = f2bf(w.y);
      t[c16 * 4 + 2][vl] = f2bf(w.z);
      t[c16 * 4 + 3][vl] = f2bf(w.w);
    }
    __syncthreads();
#pragma unroll
    for (int p = 0; p < 4; ++p) {
      const int dl = p * 16 + r16;
      const int vl = c16 * 4;
      ushort4 o;
      o.x = t[dl][vl]; o.y = t[dl][vl + 1]; o.z = t[dl][vl + 2]; o.w = t[dl][vl + 3];
      *(ushort4*)(BT + (size_t)(d0 + dl) * KP + v0 + vl) = o;
    }
  }
}

// ---------------------------------------------------------------------------
// GEMM: 256x256 tile, BK=32, 8 waves (2m x 4n), 4-buffer LDS ring (128KB),
// counted vmcnt (8/4/0, never drains mid-loop, 2-step slack), TWO fine
// phases per K-step (ds_read || gl_lds-issue || MFMA interleave, 2 barriers
// per phase), paired-row 8-slot XOR swizzle (pre-swizzled global source +
// swizzled ds_read => exactly 2-way banks = free), split-K=32, XCD-grouped
// decode, setprio around MFMA clusters, atomicAdd f32 epilogue.
// ---------------------------------------------------------------------------
__global__ __launch_bounds__(512, 1) void gemm_kernel(const u16* __restrict__ A,
                                                      const u16* __restrict__ BT,
                                                      const u64* __restrict__ amax,
                                                      float* __restrict__ out)
{
  __shared__ u16 ldsA[4][256 * 32];   // 16KB per buf
  __shared__ u16 ldsB[4][256 * 32];

  const int bx  = blockIdx.x;
  // bits[2:0]=x, [5:3]=mn, [7:6]=z; kc = x | z<<3 -> the 8 mn-blocks of one kc
  // share bx%8 -> same XCD (shared A/B k-panels stay in one L2)
  const int kc  = (bx & 7) | ((bx >> 6) << 3);     // 0..31
  const int mn  = (bx >> 3) & 7;
  const int m0  = (mn & 1) << 8;
  const int n0  = (mn >> 1) << 8;
  const int ks0 = kc * SC * 2;                     // in BK=32 steps: 50 per kc
  const int ks1 = min(NST32, ks0 + SC * 2);
  const int tid  = threadIdx.x;
  const int wid  = tid >> 6;
  const int lane = tid & 63;
  const int wr   = wid >> 2;   // 0..1
  const int wc   = wid & 3;    // 0..3

  if (bx == 0) {  // finalize predictions (512 threads, one per row)
    u64 p = amax[tid];
    out[PRED_OFF + tid] = (float)(0xFFFF - (int)(p & 0xFFFFu));
  }

  // --- staging (pre-swizzled source): lane l = p*8+s covers 16B slot s of
  // 128B row-pair p; LDS written linearly; slot s of pair p holds global
  // (row 2p+((s^p)>>2), kslot (s^p)&3)  [both-sides swizzle, rule 21]
  const int sp  = lane >> 3;                  // pair in 16-row band
  const int sx  = (lane & 7) ^ sp;            // swizzled (rowbit,kslot)
  const int srow = 2 * sp + (sx >> 2);        // row in band (0..15)
  const int skel = (sx & 3) << 3;             // k elem offset (0..24)
  const u16* gA = A  + (size_t)(m0 + wid * 32 + srow) * KP + skel;
  const u16* gB = BT + (size_t)(n0 + wid * 32 + srow) * KP + skel;

  f32x4 acc[8][4] = {};

  // --- fragment read: row r=lane&15, kslot q4=lane>>4; slot within pair:
  const int r   = lane & 15;
  const int q4  = lane >> 4;                  // 0..3
  const int sl  = (((r & 1) << 2) | q4) ^ ((r >> 1) & 7);   // per-lane const
  const int rb2A = (wr * 128 + (r & ~1)) * 32 + sl * 8;
  const int rb2B = (wc * 64  + (r & ~1)) * 32 + sl * 8;

#define STAGE_A(buf, ks) do {                                            \
    const size_t k_ = (size_t)(ks) << 5;                                 \
    gl_lds16(gA + k_,                 &ldsA[buf][(wid * 32) * 32]);      \
    gl_lds16(gA + k_ + (size_t)16*KP, &ldsA[buf][(wid * 32 + 16) * 32]); \
  } while (0)
#define STAGE_B(buf, ks) do {                                            \
    const size_t k_ = (size_t)(ks) << 5;                                 \
    gl_lds16(gB + k_,                 &ldsB[buf][(wid * 32) * 32]);      \
    gl_lds16(gB + k_ + (size_t)16*KP, &ldsB[buf][(wid * 32 + 16) * 32]); \
  } while (0)

  // prologue: stage 3 steps (A,B interleaved so oldest-4 = step ks0)
  STAGE_A(0, ks0); STAGE_B(0, ks0);
  if (ks0 + 1 < ks1) { STAGE_A(1, ks0 + 1); STAGE_B(1, ks0 + 1); }
  if (ks0 + 2 < ks1) { STAGE_A(2, ks0 + 2); STAGE_B(2, ks0 + 2); }
  if (ks0 + 2 < ks1)      asm volatile("s_waitcnt vmcnt(8)" ::: "memory");
  else if (ks0 + 1 < ks1) asm volatile("s_waitcnt vmcnt(4)" ::: "memory");
  else                    asm volatile("s_waitcnt vmcnt(0)" ::: "memory");
  __builtin_amdgcn_s_barrier();

  int b = 0;
  for (int ks = ks0; ks < ks1; ++ks) {
    const u16* lA = ldsA[b];
    const u16* lB = ldsB[b];

    // ================= PHASE 0: i0-3 x j0-3 =================
    bf16x8 av[4], bv[4];
#pragma unroll
    for (int i = 0; i < 4; ++i) av[i] = *(const bf16x8*)(lA + rb2A + i * 512);
#pragma unroll
    for (int j = 0; j < 4; ++j) bv[j] = *(const bf16x8*)(lB + rb2B + j * 512);
    if (ks + 3 < ks1) STAGE_A((b + 3) & 3, ks + 3);
    __builtin_amdgcn_s_barrier();
    asm volatile("s_waitcnt lgkmcnt(0)" ::: "memory");
    __builtin_amdgcn_sched_barrier(0);
    __builtin_amdgcn_s_setprio(1);
#pragma unroll
    for (int i = 0; i < 4; ++i)
#pragma unroll
      for (int j = 0; j < 4; ++j)
        acc[i][j] = __builtin_amdgcn_mfma_f32_16x16x32_bf16(av[i], bv[j], acc[i][j], 0, 0, 0);
    __builtin_amdgcn_s_setprio(0);
    __builtin_amdgcn_s_barrier();

    // ================= PHASE 1: i4-7 x j0-3 (bv reused) =================
    bf16x8 aw[4];
#pragma unroll
    for (int i = 0; i < 4; ++i) aw[i] = *(const bf16x8*)(lA + rb2A + (i + 4) * 512);
    if (ks + 3 < ks1) STAGE_B((b + 3) & 3, ks + 3);
    __builtin_amdgcn_s_barrier();
    asm volatile("s_waitcnt lgkmcnt(0)" ::: "memory");
    __builtin_amdgcn_sched_barrier(0);
    __builtin_amdgcn_s_setprio(1);
#pragma unroll
    for (int i = 0; i < 4; ++i)
#pragma unroll
      for (int j = 0; j < 4; ++j)
        acc[i + 4][j] = __builtin_amdgcn_mfma_f32_16x16x32_bf16(aw[i], bv[j], acc[i + 4][j], 0, 0, 0);
    __builtin_amdgcn_s_setprio(0);
    // counted wait: ensure step ks+1's 4 loads landed before releasing reads
    if (ks + 3 < ks1)      asm volatile("s_waitcnt vmcnt(8)" ::: "memory");
    else if (ks + 2 < ks1) asm volatile("s_waitcnt vmcnt(4)" ::: "memory");
    else if (ks + 1 < ks1) asm volatile("s_waitcnt vmcnt(0)" ::: "memory");
    __builtin_amdgcn_s_barrier();
    b = (b + 1) & 3;
  }
#undef STAGE_A
#undef STAGE_B

  // epilogue: split-K accumulate (pred_emb zeroed by prep)
  const int col = lane & 15;
  const int r4  = q4 << 2;
#pragma unroll
  for (int i = 0; i < 8; ++i)
#pragma unroll
    for (int j = 0; j < 4; ++j)
#pragma unroll
      for (int rr = 0; rr < 4; ++rr) {
        const int mm = m0 + wr * 128 + i * 16 + r4 + rr;
        const int nn = n0 + wc * 64 + j * 16 + col;
        atomicAdd(out + (size_t)mm * NDIM + nn, acc[i][j][rr]);
      }
}

// ---------------------------------------------------------------------------
extern "C" void kernel_launch(void* const* d_in, const int* in_sizes, int n_in,
                              void* d_out, int out_size, void* d_ws, size_t ws_size,
                              hipStream_t stream) {
  const float* P = (const float*)d_in[0];   // [512][50257]
  const float* W = (const float*)d_in[1];   // [50257][1024]
  float* out = (float*)d_out;
  u64* amax = (u64*)d_ws;                               // 512 x u64
  u16* A  = (u16*)((char*)d_ws + 4096);                 // [512][KP] bf16
  u16* BT = A + (size_t)MROWS * KP;                     // [1024][KP] bf16

  hipMemsetAsync(amax, 0, MROWS * sizeof(u64), stream);
  prep_fused<<<NPREP + NCONVW, 256, 0, stream>>>(P, W, out, A, BT, amax);
  gemm_kernel<<<256, 512, 0, stream>>>(A, BT, amax, out);
}